// Round 2
// baseline (970.775 us; speedup 1.0000x reference)
//
#include <hip/hip_runtime.h>

#define FL_N 1048576
#define FL_C 128
#define FL_ALPHA 0.25f

constexpr int BLOCKS = 2048;
constexpr int TPB    = 256;
constexpr int WAVES_PER_BLOCK = TPB / 64;
constexpr int ROWS_PER_ITER   = 8;                     // 8 rows = 4KB per wave-iteration
constexpr int ROWBLOCKS       = FL_N / ROWS_PER_ITER;  // 131072

using f32x4 = __attribute__((ext_vector_type(4))) float;
using i32x4 = __attribute__((ext_vector_type(4))) int;

__device__ __forceinline__ float exp4_sum(f32x4 p) {
    return __expf(p.x) + __expf(p.y) + __expf(p.z) + __expf(p.w);
}
__device__ __forceinline__ float dot4(f32x4 p, i32x4 l) {
    return p.x * (float)l.x + p.y * (float)l.y + p.z * (float)l.z + p.w * (float)l.w;
}

// VALU-pipe cross-lane add via DPP (verified exact in R0: absmax 0.0).
template<int CTRL>
__device__ __forceinline__ float dpp_xadd(float x) {
    int m = __builtin_amdgcn_update_dpp(0, __float_as_int(x), CTRL, 0xF, 0xF, true);
    return x + __int_as_float(m);
}
// Sum over each 32-lane half; every lane of the half ends with the half's sum.
// Stages: quad_perm xor1, quad_perm xor2, row_half_mirror (==xor4 once quads
// are uniform), row_mirror (==xor8 once 8-groups are uniform), then a single
// shfl_xor(16) to cross the 16-lane DPP row boundary (stays within the half).
__device__ __forceinline__ float group32_sum(float x) {
    x = dpp_xadd<0xB1>(x);    // quad_perm [1,0,3,2]
    x = dpp_xadd<0x4E>(x);    // quad_perm [2,3,0,1]
    x = dpp_xadd<0x141>(x);   // row_half_mirror
    x = dpp_xadd<0x140>(x);   // row_mirror
    x += __shfl_xor(x, 16, 64);
    return x;
}

__device__ __forceinline__ float focal_term(float se, float ll) {
    float pr = __expf(ll) / se;   // p = exp(label_logit) / sumexp
    float om = 1.0f - pr;
    return FL_ALPHA * om * om * (__logf(se) - ll);  // alpha*(1-p)^2*(t2+log t1)
}

// Fully-contiguous loads: instruction k reads the wave's bytes
// [k*1024, (k+1)*1024) of a 4KB 8-row block — one contiguous 1KB wave access
// (lane L at byte k*1024 + L*16). Lane L's k-th value belongs to row
// 2k + (L>>5), columns (L&31)*4 .. +3. Plain (cached) loads — no nt flag.
__global__ __launch_bounds__(TPB) void focal_partial(
    const float* __restrict__ preds,
    const int*   __restrict__ labels,
    float*       __restrict__ partial)
{
    const int tid  = threadIdx.x;
    const int wave = tid >> 6;
    const int lane = tid & 63;

    const int wavesTotal = gridDim.x * WAVES_PER_BLOCK;
    const int gwave      = blockIdx.x * WAVES_PER_BLOCK + wave;

    float acc = 0.0f;

    for (int rb = gwave; rb < ROWBLOCKS; rb += wavesTotal) {
        size_t base = (size_t)rb * (ROWS_PER_ITER * FL_C) + (size_t)lane * 4;
        const f32x4* pp = reinterpret_cast<const f32x4*>(preds  + base);
        const i32x4* lp = reinterpret_cast<const i32x4*>(labels + base);

        // 8 contiguous 1KB wave-loads (imm offsets 0/1024/2048/3072 bytes)
        f32x4 p0 = pp[0];
        f32x4 p1 = pp[64];
        f32x4 p2 = pp[128];
        f32x4 p3 = pp[192];
        i32x4 l0 = lp[0];
        i32x4 l1 = lp[64];
        i32x4 l2 = lp[128];
        i32x4 l3 = lp[192];

        float e0 = exp4_sum(p0), e1 = exp4_sum(p1), e2 = exp4_sum(p2), e3 = exp4_sum(p3);
        float d0 = dot4(p0, l0), d1 = dot4(p1, l1), d2 = dot4(p2, l2), d3 = dot4(p3, l3);

        // Per-k half-wave reductions: lanes <32 hold row 2k, lanes >=32 row 2k+1.
        e0 = group32_sum(e0);  d0 = group32_sum(d0);
        e1 = group32_sum(e1);  d1 = group32_sum(d1);
        e2 = group32_sum(e2);  d2 = group32_sum(d2);
        e3 = group32_sum(e3);  d3 = group32_sum(d3);

        // Branchless epilogue: each row's term computed by all 32 lanes of its
        // half; wave sum is exactly 32x the true sum (compensated in final).
        acc += focal_term(e0, d0) + focal_term(e1, d1)
             + focal_term(e2, d2) + focal_term(e3, d3);
    }

    // Full-wave butterfly (values duplicated 32x -> exact power-of-2 factor).
    #pragma unroll
    for (int m = 32; m >= 1; m >>= 1)
        acc += __shfl_xor(acc, m, 64);

    __shared__ float smem[WAVES_PER_BLOCK];
    if (lane == 0) smem[wave] = acc;
    __syncthreads();
    if (tid == 0) {
        float s = 0.0f;
        #pragma unroll
        for (int w = 0; w < WAVES_PER_BLOCK; ++w) s += smem[w];
        partial[blockIdx.x] = s;   // 32x true sum; plain store
    }
}

__global__ __launch_bounds__(256) void focal_final(
    const float* __restrict__ partial,
    float*       __restrict__ out)
{
    const int tid  = threadIdx.x;
    const int wave = tid >> 6;
    const int lane = tid & 63;

    float acc = 0.0f;
    for (int i = tid; i < BLOCKS; i += 256) acc += partial[i];

    #pragma unroll
    for (int m = 32; m >= 1; m >>= 1)
        acc += __shfl_xor(acc, m, 64);

    __shared__ float smem[4];
    if (lane == 0) smem[wave] = acc;
    __syncthreads();
    if (tid == 0) {
        float s = smem[0] + smem[1] + smem[2] + smem[3];
        // 1/(32*N): the 32x duplication is an exact 2^5.
        out[0] = s * (1.0f / (32.0f * (float)FL_N));
    }
}

extern "C" void kernel_launch(void* const* d_in, const int* in_sizes, int n_in,
                              void* d_out, int out_size, void* d_ws, size_t ws_size,
                              hipStream_t stream)
{
    const float* preds  = (const float*)d_in[0];
    const int*   labels = (const int*)d_in[1];
    float*       out    = (float*)d_out;
    float*       part   = (float*)d_ws;   // BLOCKS floats = 8 KiB scratch

    focal_partial<<<BLOCKS, TPB, 0, stream>>>(preds, labels, part);
    focal_final<<<1, 256, 0, stream>>>(part, out);
}

// Round 3
// 954.966 us; speedup vs baseline: 1.0166x; 1.0166x over previous
//
#include <hip/hip_runtime.h>

#define FL_N 1048576
#define FL_C 128
#define FL_ALPHA 0.25f

constexpr int BLOCKS = 2048;
constexpr int TPB    = 256;
constexpr int WAVES_PER_BLOCK = TPB / 64;
constexpr int ROWS_PER_WAVE   = 8;                     // 8 lanes per row
constexpr int ROWBLOCKS       = FL_N / ROWS_PER_WAVE;  // 131072
constexpr int WAVE_STRIDE     = BLOCKS * WAVES_PER_BLOCK;      // 8192 waves
constexpr int ITERS           = ROWBLOCKS / WAVE_STRIDE;       // exactly 16

static_assert(ROWBLOCKS % WAVE_STRIDE == 0, "uniform trip count required");

using f32x4 = __attribute__((ext_vector_type(4))) float;
using i32x4 = __attribute__((ext_vector_type(4))) int;

__device__ __forceinline__ float exp4_sum(f32x4 p) {
    return __expf(p.x) + __expf(p.y) + __expf(p.z) + __expf(p.w);
}
__device__ __forceinline__ float dot4(f32x4 p, i32x4 l) {
    return p.x * (float)l.x + p.y * (float)l.y + p.z * (float)l.z + p.w * (float)l.w;
}

// VALU-pipe cross-lane add via DPP (verified exact in R1: absmax 0.0).
template<int CTRL>
__device__ __forceinline__ float dpp_xadd(float x) {
    int m = __builtin_amdgcn_update_dpp(0, __float_as_int(x), CTRL, 0xF, 0xF, true);
    return x + __int_as_float(m);
}
// Sum within each 8-lane group; all 8 lanes end with the group sum.
__device__ __forceinline__ float group8_sum(float x) {
    x = dpp_xadd<0xB1>(x);   // quad_perm [1,0,3,2]  (xor 1)
    x = dpp_xadd<0x4E>(x);   // quad_perm [2,3,0,1]  (xor 2)
    x = dpp_xadd<0x141>(x);  // row_half_mirror      (xor 4 once quads uniform)
    return x;
}

// One iteration's register tile: 8 rows x 128 cols of preds + labels.
// Lane L owns row (L>>3), float4 chunks (L&7)+8k -> 8 scattered 16B loads.
struct Frag {
    f32x4 p0, p1, p2, p3;
    i32x4 l0, l1, l2, l3;
};

__device__ __forceinline__ Frag load_frag(const float* __restrict__ preds,
                                          const int*   __restrict__ labels,
                                          size_t base) {
    const f32x4* pp = reinterpret_cast<const f32x4*>(preds  + base);
    const i32x4* lp = reinterpret_cast<const i32x4*>(labels + base);
    Frag f;
    f.p0 = __builtin_nontemporal_load(pp + 0);
    f.p1 = __builtin_nontemporal_load(pp + 8);
    f.p2 = __builtin_nontemporal_load(pp + 16);
    f.p3 = __builtin_nontemporal_load(pp + 24);
    f.l0 = __builtin_nontemporal_load(lp + 0);
    f.l1 = __builtin_nontemporal_load(lp + 8);
    f.l2 = __builtin_nontemporal_load(lp + 16);
    f.l3 = __builtin_nontemporal_load(lp + 24);
    return f;
}

// Per-lane focal contribution (duplicated 8x across the row group; exact 2^3
// factor compensated in the final scale).
__device__ __forceinline__ float frag_term(const Frag& f) {
    float se = exp4_sum(f.p0) + exp4_sum(f.p1) + exp4_sum(f.p2) + exp4_sum(f.p3);
    float ll = dot4(f.p0, f.l0) + dot4(f.p1, f.l1) + dot4(f.p2, f.l2) + dot4(f.p3, f.l3);
    se = group8_sum(se);
    ll = group8_sum(ll);
    float pr = __expf(ll) / se;   // p = exp(label_logit) / sumexp
    float om = 1.0f - pr;
    return FL_ALPHA * om * om * (__logf(se) - ll);  // alpha*(1-p)^2*(t2+log t1)
}

// Register double-buffer: iteration k+1's 8 loads issue BEFORE iteration k's
// compute tail (exp/dot/reduce/focal), so the memory pipe never waits on the
// dependent chain. Compile-time trip count (16) -> clean pipeline.
__global__ __launch_bounds__(TPB) void focal_partial(
    const float* __restrict__ preds,
    const int*   __restrict__ labels,
    float*       __restrict__ partial)
{
    const int tid  = threadIdx.x;
    const int wave = tid >> 6;
    const int lane = tid & 63;

    const int gwave = blockIdx.x * WAVES_PER_BLOCK + wave;
    const int laneOff = (lane >> 3) * FL_C + (lane & 7) * 4;  // float offset in row-block

    constexpr size_t STEP = (size_t)WAVE_STRIDE * (ROWS_PER_WAVE * FL_C);
    size_t base = (size_t)gwave * (ROWS_PER_WAVE * FL_C) + laneOff;

    float acc = 0.0f;

    Frag a = load_frag(preds, labels, base);
    for (int it = 1; it < ITERS; ++it) {
        base += STEP;
        Frag b = load_frag(preds, labels, base);  // prefetch next tile
        acc += frag_term(a);                      // compute current
        a = b;                                    // register rename
    }
    acc += frag_term(a);

    // Full-wave butterfly; 8-lane groups hold identical values (exact 2^k).
    #pragma unroll
    for (int m = 32; m >= 1; m >>= 1)
        acc += __shfl_xor(acc, m, 64);

    __shared__ float smem[WAVES_PER_BLOCK];
    if (lane == 0) smem[wave] = acc;
    __syncthreads();
    if (tid == 0) {
        float s = 0.0f;
        #pragma unroll
        for (int w = 0; w < WAVES_PER_BLOCK; ++w) s += smem[w];
        partial[blockIdx.x] = s;   // 8x true sum; plain store
    }
}

__global__ __launch_bounds__(256) void focal_final(
    const float* __restrict__ partial,
    float*       __restrict__ out)
{
    const int tid  = threadIdx.x;
    const int wave = tid >> 6;
    const int lane = tid & 63;

    float acc = 0.0f;
    for (int i = tid; i < BLOCKS; i += 256) acc += partial[i];

    #pragma unroll
    for (int m = 32; m >= 1; m >>= 1)
        acc += __shfl_xor(acc, m, 64);

    __shared__ float smem[4];
    if (lane == 0) smem[wave] = acc;
    __syncthreads();
    if (tid == 0) {
        float s = smem[0] + smem[1] + smem[2] + smem[3];
        // 1/(8*N): the 8x duplication from the branchless epilogue is exact.
        out[0] = s * (1.0f / (8.0f * (float)FL_N));
    }
}

extern "C" void kernel_launch(void* const* d_in, const int* in_sizes, int n_in,
                              void* d_out, int out_size, void* d_ws, size_t ws_size,
                              hipStream_t stream)
{
    const float* preds  = (const float*)d_in[0];
    const int*   labels = (const int*)d_in[1];
    float*       out    = (float*)d_out;
    float*       part   = (float*)d_ws;   // BLOCKS floats = 8 KiB scratch

    focal_partial<<<BLOCKS, TPB, 0, stream>>>(preds, labels, part);
    focal_final<<<1, 256, 0, stream>>>(part, out);
}